// Round 6
// baseline (298.186 us; speedup 1.0000x reference)
//
#include <hip/hip_runtime.h>

#define S_LEN 8192
#define D_KK  128
#define SCALE 0.08838834764831845f   // 1/sqrt(128)

typedef __bf16 bf16x2 __attribute__((ext_vector_type(2)));
typedef __bf16 bf16x4 __attribute__((ext_vector_type(4)));
typedef __bf16 bf16x8 __attribute__((ext_vector_type(8)));
typedef float  f32x16 __attribute__((ext_vector_type(16)));

// ---------------------------------------------------------------------------
// Pre-pass: pack K and V into FRAGMENT-ORDER bf16 layouts so every main-loop
// wave load is a contiguous 1KB (lane-linear) read:
//   Kf[t*8+s][lane*8+j] = K[t*32 + (lane&31)][s*16 + (lane>>5)*8 + j]
//   Vf[t*8+f][lane*8+j] = V[t*32 + 16*(f&1) + 8*(lane>>5) + j][32*(f>>1) + (lane&31)]
// ---------------------------------------------------------------------------
__global__ __launch_bounds__(256) void prep_kv_23450521436217(
    const float* __restrict__ K,
    const float* __restrict__ V,
    __bf16* __restrict__ Kf,
    __bf16* __restrict__ Vf)
{
    const int tid = threadIdx.x;
    const int t   = blockIdx.x;
    __shared__ __bf16 T[32][140];

    const float* ktile = K + (size_t)t * 32 * D_KK;
    const float* vtile = V + (size_t)t * 32 * D_KK;

    const int row = tid & 31;
    const int cp  = tid >> 5;
    #pragma unroll
    for (int i = 0; i < 2; ++i) {
        int c = cp * 2 + i;
        int s = c >> 1, hi = c & 1;
        const float* src = ktile + row * D_KK + c * 8;
        float4 a = *(const float4*)(src);
        float4 b = *(const float4*)(src + 4);
        bf16x8 o;
        o[0]=(__bf16)a.x; o[1]=(__bf16)a.y; o[2]=(__bf16)a.z; o[3]=(__bf16)a.w;
        o[4]=(__bf16)b.x; o[5]=(__bf16)b.y; o[6]=(__bf16)b.z; o[7]=(__bf16)b.w;
        *(bf16x8*)(Kf + (size_t)(t * 8 + s) * 512 + hi * 256 + row * 8) = o;
    }

    #pragma unroll
    for (int i = 0; i < 4; ++i) {
        int f4 = tid + i * 256;
        float4 v = ((const float4*)vtile)[f4];
        int r = f4 >> 5, cc = (f4 & 31) << 2;
        bf16x4 b;
        b[0]=(__bf16)v.x; b[1]=(__bf16)v.y; b[2]=(__bf16)v.z; b[3]=(__bf16)v.w;
        *(bf16x4*)(&T[r][cc]) = b;
    }
    __syncthreads();

    #pragma unroll
    for (int i = 0; i < 2; ++i) {
        int idx  = tid + i * 256;
        int frag = idx >> 6, lane = idx & 63;
        int hi = lane >> 5, l5 = lane & 31;
        int d = frag >> 1, h = frag & 1;
        bf16x8 o;
        #pragma unroll
        for (int j = 0; j < 8; ++j) o[j] = T[16 * h + 8 * hi + j][32 * d + l5];
        *(bf16x8*)(Vf + (size_t)(t * 8 + frag) * 512 + lane * 8) = o;
    }
}

// ---------------------------------------------------------------------------
// Flash attention fwd, 32x32x16 MFMA. 256 blocks x 1024 thr (16 waves =
// 4 waves/SIMD, 1 block/CU). Each block: 32 q-rows; each wave: a 512-key
// strip, 16 iters of 32 keys. No LDS / no barriers in the main loop; K
// double-buffered in regs, V issued at loop top; P redistributed via 4x
// v_permlane32_swap_b32; defer-max (THR=8). All K/V loads are contiguous
// 1KB wave reads from the fragment-packed buffers.
// Merge: 16 partials -> two concurrent 8-round LDS accumulations (A,B),
// summed during the final coalesced write.
// ---------------------------------------------------------------------------
__global__ __launch_bounds__(1024, 4) void attn_fwd_23450521436217(
    const float*  __restrict__ Q,
    const __bf16* __restrict__ Kf,
    const __bf16* __restrict__ Vf,
    float* __restrict__ O)
{
    const int tid  = threadIdx.x;
    const int wave = tid >> 6;    // 0..15 -> KV strip
    const int lane = tid & 63;
    const int l5   = lane & 31;   // q column (B ops) / A row (K,V ops)
    const int hi   = lane >> 5;   // k-half within MFMA

    __shared__ float OaccA[D_KK][33];
    __shared__ float OaccB[D_KK][33];
    __shared__ float Ml[16][32], Ll[16][32], Lf[32];

    const int qrow = blockIdx.x * 32 + l5;

    // Q fragments (B operand), SCALE folded in
    bf16x8 qf[8];
    #pragma unroll
    for (int s = 0; s < 8; ++s) {
        const float* qp = Q + (size_t)qrow * D_KK + s * 16 + hi * 8;
        float4 a = *(const float4*)(qp);
        float4 b = *(const float4*)(qp + 4);
        bf16x8 f;
        f[0]=(__bf16)(a.x*SCALE); f[1]=(__bf16)(a.y*SCALE);
        f[2]=(__bf16)(a.z*SCALE); f[3]=(__bf16)(a.w*SCALE);
        f[4]=(__bf16)(b.x*SCALE); f[5]=(__bf16)(b.y*SCALE);
        f[6]=(__bf16)(b.z*SCALE); f[7]=(__bf16)(b.w*SCALE);
        qf[s] = f;
    }

    f32x16 oacc[4];
    #pragma unroll
    for (int d = 0; d < 4; ++d) oacc[d] = f32x16{};
    float m_run = -1e30f, l_run = 0.0f;

    // fragment-packed bases for this wave's 512-key strip (16 tiles)
    const __bf16* kfp = Kf + (size_t)(wave * 16) * 4096 + lane * 8;
    const __bf16* vfp = Vf + (size_t)(wave * 16) * 4096 + lane * 8;

    bf16x8 kbufA[8], kbufB[8], vb[8];

    #pragma unroll
    for (int s = 0; s < 8; ++s) kbufA[s] = *(const bf16x8*)(kfp + s * 512);

#define ATTN_BODY(KC, KN, IT, PF)                                              \
    {                                                                          \
        const __bf16* vt = vfp + (size_t)(IT) * 4096;                          \
        _Pragma("unroll")                                                      \
        for (int f = 0; f < 8; ++f)                                            \
            vb[f] = *(const bf16x8*)(vt + f * 512);                            \
        /* QK^T swapped: S^T[key][q], key=(r&3)+8*(r>>2)+4*hi, q=l5 */         \
        f32x16 c = f32x16{};                                                   \
        _Pragma("unroll")                                                      \
        for (int s = 0; s < 8; ++s)                                            \
            c = __builtin_amdgcn_mfma_f32_32x32x16_bf16(KC[s], qf[s], c,       \
                                                        0, 0, 0);             \
        /* prefetch next-iter K while softmax runs */                          \
        if (PF) {                                                              \
            const __bf16* kn = kfp + (size_t)((IT) + 1) * 4096;                \
            _Pragma("unroll")                                                  \
            for (int s = 0; s < 8; ++s)                                        \
                KN[s] = *(const bf16x8*)(kn + s * 512);                        \
        }                                                                      \
        /* online softmax: pairwise max tree (depth 4), defer-max THR=8 */     \
        float x0 = fmaxf(c[0], c[8]),  x1 = fmaxf(c[1], c[9]);                 \
        float x2 = fmaxf(c[2], c[10]), x3 = fmaxf(c[3], c[11]);                \
        float x4 = fmaxf(c[4], c[12]), x5 = fmaxf(c[5], c[13]);                \
        float x6 = fmaxf(c[6], c[14]), x7 = fmaxf(c[7], c[15]);                \
        float y0 = fmaxf(fmaxf(x0, x4), fmaxf(x1, x5));                        \
        float y1 = fmaxf(fmaxf(x2, x6), fmaxf(x3, x7));                        \
        float tmax = fmaxf(y0, y1);                                            \
        tmax = fmaxf(tmax, __shfl_xor(tmax, 32));                              \
        if (__any(tmax > m_run + 8.0f)) {                                      \
            float mnew  = fmaxf(m_run, tmax);                                  \
            float alpha = __expf(m_run - mnew);                                \
            _Pragma("unroll")                                                  \
            for (int d = 0; d < 4; ++d) oacc[d] *= alpha;                      \
            l_run *= alpha;                                                    \
            m_run  = mnew;                                                     \
        }                                                                      \
        float p[16];                                                           \
        _Pragma("unroll")                                                      \
        for (int r = 0; r < 16; ++r) p[r] = __expf(c[r] - m_run);              \
        float s0a = (p[0]+p[1]) + (p[2]+p[3]),  s1a = (p[4]+p[5]) + (p[6]+p[7]); \
        float s2a = (p[8]+p[9]) + (p[10]+p[11]), s3a = (p[12]+p[13]) + (p[14]+p[15]); \
        float ps = (s0a + s1a) + (s2a + s3a);                                  \
        ps += __shfl_xor(ps, 32);                                              \
        l_run += ps;                                                           \
        /* P -> bf16 packs; permlane32_swap -> PV B-operand words */           \
        unsigned pk[8];                                                        \
        _Pragma("unroll")                                                      \
        for (int tq = 0; tq < 8; ++tq) {                                       \
            bf16x2 w; w[0] = (__bf16)p[2*tq]; w[1] = (__bf16)p[2*tq+1];        \
            pk[tq] = __builtin_bit_cast(unsigned, w);                          \
        }                                                                      \
        asm volatile("v_permlane32_swap_b32 %0, %1" : "+v"(pk[0]), "+v"(pk[2]));\
        asm volatile("v_permlane32_swap_b32 %0, %1" : "+v"(pk[1]), "+v"(pk[3]));\
        asm volatile("v_permlane32_swap_b32 %0, %1" : "+v"(pk[4]), "+v"(pk[6]));\
        asm volatile("v_permlane32_swap_b32 %0, %1" : "+v"(pk[5]), "+v"(pk[7]));\
        union { unsigned u[4]; bf16x8 f; } b0, b1;                             \
        b0.u[0]=pk[0]; b0.u[1]=pk[1]; b0.u[2]=pk[2]; b0.u[3]=pk[3];            \
        b1.u[0]=pk[4]; b1.u[1]=pk[5]; b1.u[2]=pk[6]; b1.u[3]=pk[7];            \
        /* PV: O^T[d][q] += V^T * P^T */                                       \
        _Pragma("unroll")                                                      \
        for (int d = 0; d < 4; ++d) {                                          \
            oacc[d] = __builtin_amdgcn_mfma_f32_32x32x16_bf16(vb[2*d+0], b0.f, \
                                                              oacc[d], 0,0,0); \
            oacc[d] = __builtin_amdgcn_mfma_f32_32x32x16_bf16(vb[2*d+1], b1.f, \
                                                              oacc[d], 0,0,0); \
        }                                                                      \
    }

    for (int it = 0; it < 16; it += 2) {
        ATTN_BODY(kbufA, kbufB, it,     1);
        ATTN_BODY(kbufB, kbufA, it + 1, (it + 2 < 16));
    }
#undef ATTN_BODY

    // ---- merge 16 per-wave partials ----
    if (lane < 32) { Ml[wave][lane] = m_run; Ll[wave][lane] = l_run; }
    __syncthreads();

    float M = Ml[0][l5];
    #pragma unroll
    for (int w = 1; w < 16; ++w) M = fmaxf(M, Ml[w][l5]);
    float L = 0.0f;
    #pragma unroll
    for (int w = 0; w < 16; ++w) L += Ll[w][l5] * __expf(Ml[w][l5] - M);
    if (tid < 32) Lf[tid] = L;

    const float wscale = __expf(m_run - M);

    // two concurrent 8-round accumulations: waves 0-7 -> A, 8-15 -> B
    float (*Oa)[33] = (wave < 8) ? OaccA : OaccB;
    const int w8 = wave & 7;
    for (int r = 0; r < 8; ++r) {
        if (w8 == r) {
            #pragma unroll
            for (int d = 0; d < 4; ++d)
                #pragma unroll
                for (int reg = 0; reg < 16; ++reg) {
                    int drow = d * 32 + (reg & 3) + 8 * (reg >> 2) + 4 * hi;
                    float v = oacc[d][reg] * wscale;
                    if (r == 0) Oa[drow][l5]  = v;
                    else        Oa[drow][l5] += v;
                }
        }
        __syncthreads();
    }

    // ---- write O[q][d], one coalesced float4 per thread ----
    const int q  = tid >> 5;            // 0..31
    const int d0 = (tid & 31) * 4;
    const float invl = 1.0f / Lf[q];
    float4 o;
    o.x = (OaccA[d0+0][q] + OaccB[d0+0][q]) * invl;
    o.y = (OaccA[d0+1][q] + OaccB[d0+1][q]) * invl;
    o.z = (OaccA[d0+2][q] + OaccB[d0+2][q]) * invl;
    o.w = (OaccA[d0+3][q] + OaccB[d0+3][q]) * invl;
    *(float4*)(O + (size_t)(blockIdx.x * 32 + q) * D_KK + d0) = o;
}

extern "C" void kernel_launch(void* const* d_in, const int* in_sizes, int n_in,
                              void* d_out, int out_size, void* d_ws, size_t ws_size,
                              hipStream_t stream) {
    const float* Q = (const float*)d_in[0];
    const float* K = (const float*)d_in[1];
    const float* V = (const float*)d_in[2];
    float* O = (float*)d_out;

    __bf16* Kf = (__bf16*)d_ws;                                   // 2 MB
    __bf16* Vf = (__bf16*)((char*)d_ws + (size_t)S_LEN*D_KK*2);   // 2 MB

    hipLaunchKernelGGL(prep_kv_23450521436217, dim3(S_LEN/32), dim3(256), 0, stream,
                       K, V, Kf, Vf);
    hipLaunchKernelGGL(attn_fwd_23450521436217, dim3(S_LEN/32), dim3(1024), 0, stream,
                       Q, Kf, Vf, O);
}

// Round 7
// 64.754 us; speedup vs baseline: 4.6049x; 4.6049x over previous
//
#include <hip/hip_runtime.h>

#define S_LEN 8192
#define D_KK  128
#define SCALE 0.08838834764831845f   // 1/sqrt(128)

typedef __bf16 bf16x2 __attribute__((ext_vector_type(2)));
typedef __bf16 bf16x4 __attribute__((ext_vector_type(4)));
typedef __bf16 bf16x8 __attribute__((ext_vector_type(8)));
typedef float  f32x16 __attribute__((ext_vector_type(16)));

// ---------------------------------------------------------------------------
// Pre-pass: pack K and V into FRAGMENT-ORDER bf16 layouts so every main-loop
// wave load is a contiguous 1KB (lane-linear) read:
//   Kf[t*8+s][lane*8+j] = K[t*32 + (lane&31)][s*16 + (lane>>5)*8 + j]
//   Vf[t*8+f][lane*8+j] = V[t*32 + 16*(f&1) + 8*(lane>>5) + j][32*(f>>1) + (lane&31)]
// ---------------------------------------------------------------------------
__global__ __launch_bounds__(256) void prep_kv_23450521436217(
    const float* __restrict__ K,
    const float* __restrict__ V,
    __bf16* __restrict__ Kf,
    __bf16* __restrict__ Vf)
{
    const int tid = threadIdx.x;
    const int t   = blockIdx.x;
    __shared__ __bf16 T[32][140];

    const float* ktile = K + (size_t)t * 32 * D_KK;
    const float* vtile = V + (size_t)t * 32 * D_KK;

    const int row = tid & 31;
    const int cp  = tid >> 5;
    #pragma unroll
    for (int i = 0; i < 2; ++i) {
        int c = cp * 2 + i;
        int s = c >> 1, hi = c & 1;
        const float* src = ktile + row * D_KK + c * 8;
        float4 a = *(const float4*)(src);
        float4 b = *(const float4*)(src + 4);
        bf16x8 o;
        o[0]=(__bf16)a.x; o[1]=(__bf16)a.y; o[2]=(__bf16)a.z; o[3]=(__bf16)a.w;
        o[4]=(__bf16)b.x; o[5]=(__bf16)b.y; o[6]=(__bf16)b.z; o[7]=(__bf16)b.w;
        *(bf16x8*)(Kf + (size_t)(t * 8 + s) * 512 + hi * 256 + row * 8) = o;
    }

    #pragma unroll
    for (int i = 0; i < 4; ++i) {
        int f4 = tid + i * 256;
        float4 v = ((const float4*)vtile)[f4];
        int r = f4 >> 5, cc = (f4 & 31) << 2;
        bf16x4 b;
        b[0]=(__bf16)v.x; b[1]=(__bf16)v.y; b[2]=(__bf16)v.z; b[3]=(__bf16)v.w;
        *(bf16x4*)(&T[r][cc]) = b;
    }
    __syncthreads();

    #pragma unroll
    for (int i = 0; i < 2; ++i) {
        int idx  = tid + i * 256;
        int frag = idx >> 6, lane = idx & 63;
        int hi = lane >> 5, l5 = lane & 31;
        int d = frag >> 1, h = frag & 1;
        bf16x8 o;
        #pragma unroll
        for (int j = 0; j < 8; ++j) o[j] = T[16 * h + 8 * hi + j][32 * d + l5];
        *(bf16x8*)(Vf + (size_t)(t * 8 + frag) * 512 + lane * 8) = o;
    }
}

// ---------------------------------------------------------------------------
// Flash attention fwd, 32x32x16 MFMA, SOFTWARE-PIPELINED (2-deep).
// 256 blocks x 512 thr (8 waves, 2 waves/SIMD). Each block: 32 q-rows; each
// wave: a 1024-key strip, 32 iters of 32 keys. Per iteration, in program
// order: V(t) loads -> QK^T(t+1) MFMAs (independent of softmax, fills MFMA
// pipe) -> K(t+2) prefetch -> softmax(t) on VALU (overlaps MFMA drain) ->
// PV(t). K double-buffered; c double-buffered (c0/c1); tail peeled so all
// pipeline predicates are compile-time. s_setprio(1) around MFMA clusters.
// ---------------------------------------------------------------------------
__global__ __launch_bounds__(512, 2) void attn_fwd_23450521436217(
    const float*  __restrict__ Q,
    const __bf16* __restrict__ Kf,
    const __bf16* __restrict__ Vf,
    float* __restrict__ O)
{
    const int tid  = threadIdx.x;
    const int wave = tid >> 6;    // 0..7 -> KV strip
    const int lane = tid & 63;
    const int l5   = lane & 31;   // q column (B ops) / A row (K,V ops)
    const int hi   = lane >> 5;   // k-half within MFMA

    __shared__ float Oacc[D_KK][33];
    __shared__ float Ml[8][32], Ll[8][32], Lf[32];

    const int qrow = blockIdx.x * 32 + l5;

    // Q fragments (B operand), SCALE folded in
    bf16x8 qf[8];
    #pragma unroll
    for (int s = 0; s < 8; ++s) {
        const float* qp = Q + (size_t)qrow * D_KK + s * 16 + hi * 8;
        float4 a = *(const float4*)(qp);
        float4 b = *(const float4*)(qp + 4);
        bf16x8 f;
        f[0]=(__bf16)(a.x*SCALE); f[1]=(__bf16)(a.y*SCALE);
        f[2]=(__bf16)(a.z*SCALE); f[3]=(__bf16)(a.w*SCALE);
        f[4]=(__bf16)(b.x*SCALE); f[5]=(__bf16)(b.y*SCALE);
        f[6]=(__bf16)(b.z*SCALE); f[7]=(__bf16)(b.w*SCALE);
        qf[s] = f;
    }

    f32x16 oacc[4];
    #pragma unroll
    for (int d = 0; d < 4; ++d) oacc[d] = f32x16{};
    float m_run = -1e30f, l_run = 0.0f;

    // fragment-packed bases for this wave's strip (tile stride = 8*512 = 4096)
    const __bf16* kfp = Kf + (size_t)(wave * 32) * 4096 + lane * 8;
    const __bf16* vfp = Vf + (size_t)(wave * 32) * 4096 + lane * 8;

    bf16x8 kA[8], kB[8], vb[8];
    f32x16 c0, c1;

    // prologue: K(0)->kA, K(1)->kB, c0 = QK(tile 0)
    #pragma unroll
    for (int s = 0; s < 8; ++s) kA[s] = *(const bf16x8*)(kfp + s * 512);
    #pragma unroll
    for (int s = 0; s < 8; ++s) kB[s] = *(const bf16x8*)(kfp + 4096 + s * 512);
    c0 = f32x16{};
    __builtin_amdgcn_s_setprio(1);
    #pragma unroll
    for (int s = 0; s < 8; ++s)
        c0 = __builtin_amdgcn_mfma_f32_32x32x16_bf16(kA[s], qf[s], c0, 0, 0, 0);
    __builtin_amdgcn_s_setprio(0);

// BODY(CCUR, CNEXT, KNEXT, KPF, IT, DO_QK, DO_PF):
//   SM/PV on tile IT (scores in CCUR); QK of tile IT+1 from KNEXT into CNEXT;
//   prefetch K(IT+2) into KPF. DO_QK/DO_PF are literal 0/1.
#define ATTN_BODY(CCUR, CNEXT, KNEXT, KPF, IT, DO_QK, DO_PF)                   \
    {                                                                          \
        /* V(IT) loads: consumed by PV at the bottom (latency under QK+SM) */  \
        const __bf16* vt = vfp + (size_t)(IT) * 4096;                          \
        _Pragma("unroll")                                                      \
        for (int f = 0; f < 8; ++f)                                            \
            vb[f] = *(const bf16x8*)(vt + f * 512);                            \
        /* QK^T(IT+1): independent of softmax(IT) -> fills MFMA pipe */        \
        if (DO_QK) {                                                           \
            CNEXT = f32x16{};                                                  \
            __builtin_amdgcn_s_setprio(1);                                     \
            _Pragma("unroll")                                                  \
            for (int s = 0; s < 8; ++s)                                        \
                CNEXT = __builtin_amdgcn_mfma_f32_32x32x16_bf16(KNEXT[s],      \
                                                        qf[s], CNEXT, 0,0,0); \
            __builtin_amdgcn_s_setprio(0);                                     \
        }                                                                      \
        /* K(IT+2) prefetch into the buffer QK(IT) freed last body */          \
        if (DO_PF) {                                                           \
            const __bf16* kn = kfp + (size_t)((IT) + 2) * 4096;                \
            _Pragma("unroll")                                                  \
            for (int s = 0; s < 8; ++s)                                        \
                KPF[s] = *(const bf16x8*)(kn + s * 512);                       \
        }                                                                      \
        /* softmax(IT) on CCUR: pairwise trees, defer-max THR=8 */             \
        float x0 = fmaxf(CCUR[0], CCUR[8]),  x1 = fmaxf(CCUR[1], CCUR[9]);     \
        float x2 = fmaxf(CCUR[2], CCUR[10]), x3 = fmaxf(CCUR[3], CCUR[11]);    \
        float x4 = fmaxf(CCUR[4], CCUR[12]), x5 = fmaxf(CCUR[5], CCUR[13]);    \
        float x6 = fmaxf(CCUR[6], CCUR[14]), x7 = fmaxf(CCUR[7], CCUR[15]);    \
        float y0 = fmaxf(fmaxf(x0, x4), fmaxf(x1, x5));                        \
        float y1 = fmaxf(fmaxf(x2, x6), fmaxf(x3, x7));                        \
        float tmax = fmaxf(y0, y1);                                            \
        tmax = fmaxf(tmax, __shfl_xor(tmax, 32));                              \
        if (__any(tmax > m_run + 8.0f)) {                                      \
            float mnew  = fmaxf(m_run, tmax);                                  \
            float alpha = __expf(m_run - mnew);                                \
            _Pragma("unroll")                                                  \
            for (int d = 0; d < 4; ++d) oacc[d] *= alpha;                      \
            l_run *= alpha;                                                    \
            m_run  = mnew;                                                     \
        }                                                                      \
        float p[16];                                                           \
        _Pragma("unroll")                                                      \
        for (int r = 0; r < 16; ++r) p[r] = __expf(CCUR[r] - m_run);           \
        float s0a = (p[0]+p[1]) + (p[2]+p[3]),  s1a = (p[4]+p[5]) + (p[6]+p[7]); \
        float s2a = (p[8]+p[9]) + (p[10]+p[11]), s3a = (p[12]+p[13]) + (p[14]+p[15]); \
        float ps = (s0a + s1a) + (s2a + s3a);                                  \
        ps += __shfl_xor(ps, 32);                                              \
        l_run += ps;                                                           \
        /* P -> bf16 packs; permlane32_swap -> PV B-operand words */           \
        unsigned pk[8];                                                        \
        _Pragma("unroll")                                                      \
        for (int tq = 0; tq < 8; ++tq) {                                       \
            bf16x2 w; w[0] = (__bf16)p[2*tq]; w[1] = (__bf16)p[2*tq+1];        \
            pk[tq] = __builtin_bit_cast(unsigned, w);                          \
        }                                                                      \
        asm volatile("v_permlane32_swap_b32 %0, %1" : "+v"(pk[0]), "+v"(pk[2]));\
        asm volatile("v_permlane32_swap_b32 %0, %1" : "+v"(pk[1]), "+v"(pk[3]));\
        asm volatile("v_permlane32_swap_b32 %0, %1" : "+v"(pk[4]), "+v"(pk[6]));\
        asm volatile("v_permlane32_swap_b32 %0, %1" : "+v"(pk[5]), "+v"(pk[7]));\
        union { unsigned u[4]; bf16x8 f; } b0, b1;                             \
        b0.u[0]=pk[0]; b0.u[1]=pk[1]; b0.u[2]=pk[2]; b0.u[3]=pk[3];            \
        b1.u[0]=pk[4]; b1.u[1]=pk[5]; b1.u[2]=pk[6]; b1.u[3]=pk[7];            \
        /* PV(IT): O^T += V^T * P^T */                                         \
        __builtin_amdgcn_s_setprio(1);                                         \
        _Pragma("unroll")                                                      \
        for (int d = 0; d < 4; ++d) {                                          \
            oacc[d] = __builtin_amdgcn_mfma_f32_32x32x16_bf16(vb[2*d+0], b0.f, \
                                                              oacc[d], 0,0,0); \
            oacc[d] = __builtin_amdgcn_mfma_f32_32x32x16_bf16(vb[2*d+1], b1.f, \
                                                              oacc[d], 0,0,0); \
        }                                                                      \
        __builtin_amdgcn_s_setprio(0);                                         \
    }

    for (int it = 0; it < 30; it += 2) {
        ATTN_BODY(c0, c1, kB, kA, it,     1, 1);
        ATTN_BODY(c1, c0, kA, kB, it + 1, 1, 1);
    }
    ATTN_BODY(c0, c1, kB, kA, 30, 1, 0);   // QK(31) from kB, no K prefetch
    ATTN_BODY(c1, c0, kA, kB, 31, 0, 0);   // SM/PV only
#undef ATTN_BODY

    // ---- merge 8 per-wave partials ----
    if (lane < 32) { Ml[wave][lane] = m_run; Ll[wave][lane] = l_run; }
    __syncthreads();

    float M = Ml[0][l5];
    #pragma unroll
    for (int w = 1; w < 8; ++w) M = fmaxf(M, Ml[w][l5]);
    float L = 0.0f;
    #pragma unroll
    for (int w = 0; w < 8; ++w) L += Ll[w][l5] * __expf(Ml[w][l5] - M);
    if (tid < 32) Lf[tid] = L;

    const float wscale = __expf(m_run - M);

    for (int r = 0; r < 8; ++r) {
        if (wave == r) {
            #pragma unroll
            for (int d = 0; d < 4; ++d)
                #pragma unroll
                for (int reg = 0; reg < 16; ++reg) {
                    int drow = d * 32 + (reg & 3) + 8 * (reg >> 2) + 4 * hi;
                    float v = oacc[d][reg] * wscale;
                    if (r == 0) Oacc[drow][l5]  = v;
                    else        Oacc[drow][l5] += v;
                }
        }
        __syncthreads();
    }

    // ---- write O[q][d], coalesced 2x float4 per thread ----
    const int q  = tid >> 4;            // 0..31
    const int d0 = (tid & 15) * 8;
    const float invl = 1.0f / Lf[q];
    float4 o1, o2;
    o1.x = Oacc[d0+0][q] * invl; o1.y = Oacc[d0+1][q] * invl;
    o1.z = Oacc[d0+2][q] * invl; o1.w = Oacc[d0+3][q] * invl;
    o2.x = Oacc[d0+4][q] * invl; o2.y = Oacc[d0+5][q] * invl;
    o2.z = Oacc[d0+6][q] * invl; o2.w = Oacc[d0+7][q] * invl;
    float* op = O + (size_t)(blockIdx.x * 32 + q) * D_KK + d0;
    *(float4*)(op)     = o1;
    *(float4*)(op + 4) = o2;
}

extern "C" void kernel_launch(void* const* d_in, const int* in_sizes, int n_in,
                              void* d_out, int out_size, void* d_ws, size_t ws_size,
                              hipStream_t stream) {
    const float* Q = (const float*)d_in[0];
    const float* K = (const float*)d_in[1];
    const float* V = (const float*)d_in[2];
    float* O = (float*)d_out;

    __bf16* Kf = (__bf16*)d_ws;                                   // 2 MB
    __bf16* Vf = (__bf16*)((char*)d_ws + (size_t)S_LEN*D_KK*2);   // 2 MB

    hipLaunchKernelGGL(prep_kv_23450521436217, dim3(S_LEN/32), dim3(256), 0, stream,
                       K, V, Kf, Vf);
    hipLaunchKernelGGL(attn_fwd_23450521436217, dim3(S_LEN/32), dim3(512), 0, stream,
                       Q, Kf, Vf, O);
}

// Round 8
// 63.834 us; speedup vs baseline: 4.6712x; 1.0144x over previous
//
#include <hip/hip_runtime.h>

#define S_LEN 8192
#define D_KK  128
#define SCALE 0.08838834764831845f   // 1/sqrt(128)

typedef __bf16 bf16x2 __attribute__((ext_vector_type(2)));
typedef __bf16 bf16x4 __attribute__((ext_vector_type(4)));
typedef __bf16 bf16x8 __attribute__((ext_vector_type(8)));
typedef float  f32x16 __attribute__((ext_vector_type(16)));
typedef _Float16 half_t;

// ---------------------------------------------------------------------------
// Pre-pass: pack K and V into FRAGMENT-ORDER bf16 layouts (unchanged).
//   Kf[t*8+s][lane*8+j] = K[t*32 + (lane&31)][s*16 + (lane>>5)*8 + j]
//   Vf[t*8+f][lane*8+j] = V[t*32 + 16*(f&1) + 8*(lane>>5) + j][32*(f>>1) + (lane&31)]
// ---------------------------------------------------------------------------
__global__ __launch_bounds__(256) void prep_kv_23450521436217(
    const float* __restrict__ K,
    const float* __restrict__ V,
    __bf16* __restrict__ Kf,
    __bf16* __restrict__ Vf)
{
    const int tid = threadIdx.x;
    const int t   = blockIdx.x;
    __shared__ __bf16 T[32][140];

    const float* ktile = K + (size_t)t * 32 * D_KK;
    const float* vtile = V + (size_t)t * 32 * D_KK;

    const int row = tid & 31;
    const int cp  = tid >> 5;
    #pragma unroll
    for (int i = 0; i < 2; ++i) {
        int c = cp * 2 + i;
        int s = c >> 1, hi = c & 1;
        const float* src = ktile + row * D_KK + c * 8;
        float4 a = *(const float4*)(src);
        float4 b = *(const float4*)(src + 4);
        bf16x8 o;
        o[0]=(__bf16)a.x; o[1]=(__bf16)a.y; o[2]=(__bf16)a.z; o[3]=(__bf16)a.w;
        o[4]=(__bf16)b.x; o[5]=(__bf16)b.y; o[6]=(__bf16)b.z; o[7]=(__bf16)b.w;
        *(bf16x8*)(Kf + (size_t)(t * 8 + s) * 512 + hi * 256 + row * 8) = o;
    }

    #pragma unroll
    for (int i = 0; i < 4; ++i) {
        int f4 = tid + i * 256;
        float4 v = ((const float4*)vtile)[f4];
        int r = f4 >> 5, cc = (f4 & 31) << 2;
        bf16x4 b;
        b[0]=(__bf16)v.x; b[1]=(__bf16)v.y; b[2]=(__bf16)v.z; b[3]=(__bf16)v.w;
        *(bf16x4*)(&T[r][cc]) = b;
    }
    __syncthreads();

    #pragma unroll
    for (int i = 0; i < 2; ++i) {
        int idx  = tid + i * 256;
        int frag = idx >> 6, lane = idx & 63;
        int hi = lane >> 5, l5 = lane & 31;
        int d = frag >> 1, h = frag & 1;
        bf16x8 o;
        #pragma unroll
        for (int j = 0; j < 8; ++j) o[j] = T[16 * h + 8 * hi + j][32 * d + l5];
        *(bf16x8*)(Vf + (size_t)(t * 8 + frag) * 512 + lane * 8) = o;
    }
}

// ---------------------------------------------------------------------------
// Phase A: partial flash attention. Grid = 32 q-tiles x 8 kv-splits (ks =
// bid&7 -> XCD round-robin: each XCD's blocks share one 512KB K/V slice ->
// L2-resident). Block = 512 thr (8 waves): ALL waves iterate the SAME
// 1024-key strip (32 iters); wave w owns q-subtile qt*256 + w*32.
// K tiles staged once per block into double-buffered LDS via
// global_load_lds (TA dedup 8x); V fragments on the TA path (split pipes).
// Writes per-split partials (m, l, unnormalized O^T as fp16) to workspace.
// ---------------------------------------------------------------------------
__global__ __launch_bounds__(512, 2) void attn_part_23450521436217(
    const float*  __restrict__ Q,
    const __bf16* __restrict__ Kf,
    const __bf16* __restrict__ Vf,
    half_t* __restrict__ P16,
    float*  __restrict__ Mp,
    float*  __restrict__ Lp)
{
    const int tid  = threadIdx.x;
    const int wave = tid >> 6;    // 0..7 -> q-subtile
    const int lane = tid & 63;
    const int l5   = lane & 31;   // q column (B ops) / A row (K,V ops)
    const int hi   = lane >> 5;   // k-half within MFMA

    const int ks   = blockIdx.x & 7;   // kv split (XCD-aligned)
    const int qt   = blockIdx.x >> 3;  // q-tile 0..31
    const int qsub = qt * 8 + wave;    // global 32-row q-subtile id
    const int qrow = qsub * 32 + l5;

    __shared__ __align__(16) __bf16 Klds[2][4096];   // 2 x 8KB K tiles

    // Q fragments (B operand), SCALE folded in
    bf16x8 qf[8];
    #pragma unroll
    for (int s = 0; s < 8; ++s) {
        const float* qp = Q + (size_t)qrow * D_KK + s * 16 + hi * 8;
        float4 a = *(const float4*)(qp);
        float4 b = *(const float4*)(qp + 4);
        bf16x8 f;
        f[0]=(__bf16)(a.x*SCALE); f[1]=(__bf16)(a.y*SCALE);
        f[2]=(__bf16)(a.z*SCALE); f[3]=(__bf16)(a.w*SCALE);
        f[4]=(__bf16)(b.x*SCALE); f[5]=(__bf16)(b.y*SCALE);
        f[6]=(__bf16)(b.z*SCALE); f[7]=(__bf16)(b.w*SCALE);
        qf[s] = f;
    }

    f32x16 oacc[4];
    #pragma unroll
    for (int d = 0; d < 4; ++d) oacc[d] = f32x16{};
    float m_run = -1e30f, l_run = 0.0f;

    const __bf16* kbase = Kf + (size_t)(ks * 32) * 4096;          // 32 tiles
    const __bf16* vfp   = Vf + (size_t)(ks * 32) * 4096 + lane * 8;

    // prologue: stage K tile 0 (each wave stages its 1KB fragment-block)
    {
        const __bf16* src = kbase + wave * 512 + lane * 8;
        __builtin_amdgcn_global_load_lds(
            (const __attribute__((address_space(1))) void*)src,
            (__attribute__((address_space(3))) void*)&Klds[0][wave * 512],
            16, 0, 0);
    }
    __syncthreads();

    for (int it = 0; it < 32; ++it) {
        const int cur = it & 1;

        // stage K(it+1) into the other buffer (completes at the barrier)
        if (it < 31) {
            const __bf16* src = kbase + (size_t)(it + 1) * 4096 + wave * 512 + lane * 8;
            __builtin_amdgcn_global_load_lds(
                (const __attribute__((address_space(1))) void*)src,
                (__attribute__((address_space(3))) void*)&Klds[cur ^ 1][wave * 512],
                16, 0, 0);
        }

        // V fragments for this iter (TA path; latency hidden under QK+SM)
        const __bf16* vt = vfp + (size_t)it * 4096;
        bf16x8 vb[8];
        #pragma unroll
        for (int f = 0; f < 8; ++f) vb[f] = *(const bf16x8*)(vt + f * 512);

        // QK^T swapped from LDS: S^T[key][q], key=(r&3)+8*(r>>2)+4*hi, q=l5
        f32x16 c = f32x16{};
        __builtin_amdgcn_s_setprio(1);
        #pragma unroll
        for (int s = 0; s < 8; ++s) {
            bf16x8 kf = *(const bf16x8*)(&Klds[cur][s * 512 + lane * 8]);
            c = __builtin_amdgcn_mfma_f32_32x32x16_bf16(kf, qf[s], c, 0, 0, 0);
        }
        __builtin_amdgcn_s_setprio(0);

        // online softmax: pairwise max tree, defer-max THR=8
        float x0 = fmaxf(c[0], c[8]),  x1 = fmaxf(c[1], c[9]);
        float x2 = fmaxf(c[2], c[10]), x3 = fmaxf(c[3], c[11]);
        float x4 = fmaxf(c[4], c[12]), x5 = fmaxf(c[5], c[13]);
        float x6 = fmaxf(c[6], c[14]), x7 = fmaxf(c[7], c[15]);
        float y0 = fmaxf(fmaxf(x0, x4), fmaxf(x1, x5));
        float y1 = fmaxf(fmaxf(x2, x6), fmaxf(x3, x7));
        float tmax = fmaxf(y0, y1);
        tmax = fmaxf(tmax, __shfl_xor(tmax, 32));
        if (__any(tmax > m_run + 8.0f)) {
            float mnew  = fmaxf(m_run, tmax);
            float alpha = __expf(m_run - mnew);
            #pragma unroll
            for (int d = 0; d < 4; ++d) oacc[d] *= alpha;
            l_run *= alpha;
            m_run  = mnew;
        }
        float p[16];
        #pragma unroll
        for (int r = 0; r < 16; ++r) p[r] = __expf(c[r] - m_run);
        float s0a = (p[0]+p[1]) + (p[2]+p[3]),   s1a = (p[4]+p[5]) + (p[6]+p[7]);
        float s2a = (p[8]+p[9]) + (p[10]+p[11]), s3a = (p[12]+p[13]) + (p[14]+p[15]);
        float ps = (s0a + s1a) + (s2a + s3a);
        ps += __shfl_xor(ps, 32);
        l_run += ps;

        // P -> bf16 packs; permlane32_swap -> PV B-operand words
        unsigned pk[8];
        #pragma unroll
        for (int tq = 0; tq < 8; ++tq) {
            bf16x2 w; w[0] = (__bf16)p[2*tq]; w[1] = (__bf16)p[2*tq+1];
            pk[tq] = __builtin_bit_cast(unsigned, w);
        }
        asm volatile("v_permlane32_swap_b32 %0, %1" : "+v"(pk[0]), "+v"(pk[2]));
        asm volatile("v_permlane32_swap_b32 %0, %1" : "+v"(pk[1]), "+v"(pk[3]));
        asm volatile("v_permlane32_swap_b32 %0, %1" : "+v"(pk[4]), "+v"(pk[6]));
        asm volatile("v_permlane32_swap_b32 %0, %1" : "+v"(pk[5]), "+v"(pk[7]));
        union { unsigned u[4]; bf16x8 f; } b0, b1;
        b0.u[0]=pk[0]; b0.u[1]=pk[1]; b0.u[2]=pk[2]; b0.u[3]=pk[3];
        b1.u[0]=pk[4]; b1.u[1]=pk[5]; b1.u[2]=pk[6]; b1.u[3]=pk[7];

        // PV: O^T[d][q] += V^T * P^T
        __builtin_amdgcn_s_setprio(1);
        #pragma unroll
        for (int d = 0; d < 4; ++d) {
            oacc[d] = __builtin_amdgcn_mfma_f32_32x32x16_bf16(vb[2*d+0], b0.f,
                                                              oacc[d], 0,0,0);
            oacc[d] = __builtin_amdgcn_mfma_f32_32x32x16_bf16(vb[2*d+1], b1.f,
                                                              oacc[d], 0,0,0);
        }
        __builtin_amdgcn_s_setprio(0);

        __syncthreads();   // K(it+1) staged + all waves done with buf[cur]
    }

    // ---- write partials ----
    if (lane < 32) {
        Mp[ks * S_LEN + qrow] = m_run;
        Lp[ks * S_LEN + qrow] = l_run;
    }
    half_t* pb = P16 + (size_t)(ks * 256 + qsub) * (128 * 32);
    #pragma unroll
    for (int d = 0; d < 4; ++d)
        #pragma unroll
        for (int reg = 0; reg < 16; ++reg) {
            int drow = d * 32 + (reg & 3) + 8 * (reg >> 2) + 4 * hi;
            pb[drow * 32 + l5] = (half_t)oacc[d][reg];
        }
}

// ---------------------------------------------------------------------------
// Phase B: merge 8 kv-split partials per q-row. One block per 32-row q-subtile.
// O[q][d] = (sum_ks e^{m_ks - M} * P_ks[d][q]) / (sum_ks l_ks e^{m_ks - M})
// ---------------------------------------------------------------------------
__global__ __launch_bounds__(256) void attn_merge_23450521436217(
    const half_t* __restrict__ P16,
    const float*  __restrict__ Mp,
    const float*  __restrict__ Lp,
    float* __restrict__ O)
{
    const int tid  = threadIdx.x;
    const int qsub = blockIdx.x;

    __shared__ float W[8][32];
    __shared__ float Li[32];
    __shared__ float Ot[128][33];

    if (tid < 32) {
        const int qrow = qsub * 32 + tid;
        float m[8], l[8];
        #pragma unroll
        for (int ks = 0; ks < 8; ++ks) {
            m[ks] = Mp[ks * S_LEN + qrow];
            l[ks] = Lp[ks * S_LEN + qrow];
        }
        float M = m[0];
        #pragma unroll
        for (int ks = 1; ks < 8; ++ks) M = fmaxf(M, m[ks]);
        float L = 0.0f;
        #pragma unroll
        for (int ks = 0; ks < 8; ++ks) {
            float w = __expf(m[ks] - M);
            W[ks][tid] = w;
            L += l[ks] * w;
        }
        Li[tid] = 1.0f / L;
    }
    __syncthreads();

    const int q  = tid & 31;
    const int dg = tid >> 5;          // 0..7
    #pragma unroll
    for (int j = 0; j < 16; ++j) {
        const int d = dg * 16 + j;
        float acc = 0.0f;
        #pragma unroll
        for (int ks = 0; ks < 8; ++ks)
            acc += W[ks][q] *
                   (float)P16[(size_t)(ks * 256 + qsub) * (128 * 32) + d * 32 + q];
        Ot[d][q] = acc;
    }
    __syncthreads();

    const int qq = tid >> 3;
    const int dv = (tid & 7) * 16;
    const float il = Li[qq];
    float* op = O + (size_t)(qsub * 32 + qq) * D_KK + dv;
    #pragma unroll
    for (int i = 0; i < 4; ++i) {
        float4 o;
        o.x = Ot[dv + i*4 + 0][qq] * il;
        o.y = Ot[dv + i*4 + 1][qq] * il;
        o.z = Ot[dv + i*4 + 2][qq] * il;
        o.w = Ot[dv + i*4 + 3][qq] * il;
        ((float4*)op)[i] = o;
    }
}

extern "C" void kernel_launch(void* const* d_in, const int* in_sizes, int n_in,
                              void* d_out, int out_size, void* d_ws, size_t ws_size,
                              hipStream_t stream) {
    const float* Q = (const float*)d_in[0];
    const float* K = (const float*)d_in[1];
    const float* V = (const float*)d_in[2];
    float* O = (float*)d_out;

    char* ws = (char*)d_ws;
    const size_t kf_b = (size_t)S_LEN * D_KK * 2;        // 2 MB
    __bf16* Kf = (__bf16*)(ws);
    __bf16* Vf = (__bf16*)(ws + kf_b);
    float*  Mp = (float*) (ws + 2 * kf_b);               // 8*8192*4 = 256 KB
    float*  Lp = (float*) (ws + 2 * kf_b + 8 * S_LEN * 4);
    half_t* P16= (half_t*)(ws + 2 * kf_b + 16 * S_LEN * 4);  // 16.8 MB

    hipLaunchKernelGGL(prep_kv_23450521436217, dim3(S_LEN/32), dim3(256), 0, stream,
                       K, V, Kf, Vf);
    hipLaunchKernelGGL(attn_part_23450521436217, dim3(256), dim3(512), 0, stream,
                       Q, Kf, Vf, P16, Mp, Lp);
    hipLaunchKernelGGL(attn_merge_23450521436217, dim3(S_LEN/32), dim3(256), 0, stream,
                       P16, Mp, Lp, O);
}